// Round 1
// 281.129 us; speedup vs baseline: 1.1514x; 1.1514x over previous
//
#include <hip/hip_runtime.h>
#include <hip/hip_bf16.h>
#include <cstdint>

// ---- problem constants ----
#define BB 32
#define NN 1024
#define CC 768
#define MM 64
#define HH 12
#define DD 64

typedef float f4v __attribute__((ext_vector_type(4)));
typedef __bf16 bf8 __attribute__((ext_vector_type(8)));
typedef __bf16 bf4 __attribute__((ext_vector_type(4)));

__device__ __forceinline__ f4v mfma16(bf8 a, bf8 b, f4v c) {
    return __builtin_amdgcn_mfma_f32_16x16x32_bf16(a, b, c, 0, 0, 0);
}
__device__ __forceinline__ __bf16 f2bf(float f) { return (__bf16)f; }

__device__ __forceinline__ void gl2lds16(const void* g, void* lds) {
    __builtin_amdgcn_global_load_lds((const __attribute__((address_space(1))) void*)g,
                                     (__attribute__((address_space(3))) void*)lds, 16, 0, 0);
}

// ---------- all weight fp32 -> bf16 in ONE launch ----------
__global__ __launch_bounds__(256) void k_cvtW(
        const float* __restrict__ Wc, const float* __restrict__ Wq,
        const float* __restrict__ Wk, const float* __restrict__ Wv,
        const float* __restrict__ Wp,
        __bf16* __restrict__ wc, __bf16* __restrict__ wq,
        __bf16* __restrict__ wk, __bf16* __restrict__ wv,
        __bf16* __restrict__ wp) {
    const float* in; __bf16* out; int n4;
    switch (blockIdx.y) {
        case 0: in = Wc; out = wc; n4 = MM * CC / 4; break;
        case 1: in = Wq; out = wq; n4 = CC * CC / 4; break;
        case 2: in = Wk; out = wk; n4 = CC * CC / 4; break;
        case 3: in = Wv; out = wv; n4 = CC * CC / 4; break;
        default: in = Wp; out = wp; n4 = CC * CC / 4; break;
    }
    int i = blockIdx.x * 256 + threadIdx.x;
    if (i < n4) {
        float4 v = *(const float4*)&in[i * 4];
        bf4 o; o[0] = f2bf(v.x); o[1] = f2bf(v.y); o[2] = f2bf(v.z); o[3] = f2bf(v.w);
        *(bf4*)&out[i * 4] = o;
    }
}

// ---------- K0: x -> xb (b,n,c) bf16  AND  xt (b,c,n) bf16 (tiled transpose, full-line stores) ----------
#define TS 80
__global__ __launch_bounds__(256) void k_cvtx(const float* __restrict__ x,
        __bf16* __restrict__ xb, __bf16* __restrict__ xt) {
    int c0 = blockIdx.x * 64, n0 = blockIdx.y * 64, b = blockIdx.z;
    __shared__ __align__(16) __bf16 tile[64 * TS];
    int t = threadIdx.x;
#pragma unroll
    for (int i = 0; i < 4; i++) {
        int idx = t + 256 * i, r = idx >> 4, cq = idx & 15;
        float4 v = *(const float4*)&x[((size_t)(b * NN + n0 + r)) * CC + c0 + cq * 4];
        __bf16* d = &tile[r * TS + cq * 4];
        d[0] = f2bf(v.x); d[1] = f2bf(v.y); d[2] = f2bf(v.z); d[3] = f2bf(v.w);
    }
    __syncthreads();
#pragma unroll
    for (int i = 0; i < 2; i++) {
        int idx = t + 256 * i, r = idx >> 3, ch = idx & 7;
        *(bf8*)&xb[((size_t)(b * NN + n0 + r)) * CC + c0 + ch * 8] = *(const bf8*)&tile[r * TS + ch * 8];
    }
    // xt: one full 128B line (64 n) per c-row
#pragma unroll
    for (int i = 0; i < 2; i++) {
        int idx = t + 256 * i, c = idx >> 3, ch = idx & 7;
        bf8 v;
#pragma unroll
        for (int j = 0; j < 8; j++) v[j] = tile[(ch * 8 + j) * TS + c];
        *(bf8*)&xt[((size_t)(b * CC + c0 + c)) * NN + n0 + ch * 8] = v;
    }
}

// ---------- K1: c_bmn[b,m,n] = sigmoid(x@Wc^T + bc)/N   (LDS-free) ----------
__global__ __launch_bounds__(256) void k_cluster(const __bf16* __restrict__ xb,
        const __bf16* __restrict__ Wc, const float* __restrict__ bc,
        __bf16* __restrict__ cbmn) {
    int n0 = blockIdx.x * 128, b = blockIdx.y;
    int t = threadIdx.x, w = t >> 6, l = t & 63, quad = l >> 4, l16 = l & 15;
    f4v acc[2][4];
#pragma unroll
    for (int i = 0; i < 2; i++) for (int j = 0; j < 4; j++) acc[i][j] = (f4v)0.0f;
    for (int k0 = 0; k0 < CC; k0 += 32) {
        bf8 afr[2], bfr[4];
#pragma unroll
        for (int sr = 0; sr < 2; sr++)
            afr[sr] = *(const bf8*)&xb[((size_t)(b * NN + n0 + w * 32 + sr * 16 + l16)) * CC + k0 + quad * 8];
#pragma unroll
        for (int sc = 0; sc < 4; sc++)
            bfr[sc] = *(const bf8*)&Wc[(size_t)(sc * 16 + l16) * CC + k0 + quad * 8];
#pragma unroll
        for (int sr = 0; sr < 2; sr++)
#pragma unroll
            for (int sc = 0; sc < 4; sc++)
                acc[sr][sc] = mfma16(afr[sr], bfr[sc], acc[sr][sc]);
    }
#pragma unroll
    for (int sr = 0; sr < 2; sr++)
#pragma unroll
        for (int sc = 0; sc < 4; sc++) {
            int m = sc * 16 + l16;
            float bias = bc[m];
            bf4 p;
#pragma unroll
            for (int r = 0; r < 4; r++) {
                float val = acc[sr][sc][r] + bias;
                val = 1.0f / (1.0f + __expf(-val));
                p[r] = f2bf(val * (1.0f / 1024.0f));
            }
            *(bf4*)&cbmn[((size_t)(b * MM + m)) * NN + n0 + w * 32 + sr * 16 + quad * 4] = p;
        }
}

// ---------- K2: z[b,m,c] = sum_n c_bmn[b,m,n] * xt[b,c,n]   (LDS-free, fp32 out) ----------
__global__ __launch_bounds__(256) void k_z(const __bf16* __restrict__ cbmn,
        const __bf16* __restrict__ xt, float* __restrict__ z) {
    int c0 = blockIdx.x * 64, b = blockIdx.y;
    int t = threadIdx.x, w = t >> 6, l = t & 63, quad = l >> 4, l16 = l & 15;
    f4v acc[4];
#pragma unroll
    for (int j = 0; j < 4; j++) acc[j] = (f4v)0.0f;
    for (int n0 = 0; n0 < NN; n0 += 32) {
        bf8 afr = *(const bf8*)&cbmn[((size_t)(b * MM + w * 16 + l16)) * NN + n0 + quad * 8];
#pragma unroll
        for (int sc = 0; sc < 4; sc++) {
            bf8 bfr = *(const bf8*)&xt[((size_t)(b * CC + c0 + sc * 16 + l16)) * NN + n0 + quad * 8];
            acc[sc] = mfma16(afr, bfr, acc[sc]);
        }
    }
#pragma unroll
    for (int sc = 0; sc < 4; sc++) {
        int cc = c0 + sc * 16 + l16;
#pragma unroll
        for (int r = 0; r < 4; r++) {
            int m = w * 16 + quad * 4 + r;
            z[((size_t)(b * MM + m)) * CC + cc] = acc[sc][r];
        }
    }
}

// ---------- K2b: L2-normalize rows of z, write bf16 ----------
__global__ __launch_bounds__(256) void k_znorm(const float* __restrict__ z, __bf16* __restrict__ zb) {
    int w = threadIdx.x >> 6, l = threadIdx.x & 63;
    int row = blockIdx.x * 4 + w;
    const float* zr = &z[(size_t)row * CC];
    float v[12]; float ss = 0.f;
#pragma unroll
    for (int i = 0; i < 12; i++) { v[i] = zr[l + i * 64]; ss += v[i] * v[i]; }
#pragma unroll
    for (int off = 32; off; off >>= 1) ss += __shfl_xor(ss, off);
    float s = 1.0f / fmaxf(sqrtf(ss), 1e-12f);
    __bf16* zo = &zb[(size_t)row * CC];
#pragma unroll
    for (int i = 0; i < 12; i++) zo[l + i * 64] = f2bf(v[i] * s);
}

// ---------- K3: k = z@Wk^T+bk -> (b,h,m,d); v = z@Wv^T+bv -> TRANSPOSED (b,h,d,m) ----------
__global__ __launch_bounds__(256) void k_kv(const __bf16* __restrict__ zb,
        const __bf16* __restrict__ Wk, const float* __restrict__ bk,
        const __bf16* __restrict__ Wv, const float* __restrict__ bv,
        __bf16* __restrict__ kout, __bf16* __restrict__ vtout) {
    int ct = blockIdx.x, b = blockIdx.y, which = blockIdx.z;
    const __bf16* W = which ? Wv : Wk;
    const float* bias = which ? bv : bk;
    int t = threadIdx.x, w = t >> 6, l = t & 63, quad = l >> 4, l16 = l & 15;
    f4v acc[4][2];
#pragma unroll
    for (int i = 0; i < 4; i++) for (int j = 0; j < 2; j++) acc[i][j] = (f4v)0.0f;
    for (int k0 = 0; k0 < CC; k0 += 32) {
        bf8 afr[4], bfr[2];
#pragma unroll
        for (int sr = 0; sr < 4; sr++)
            afr[sr] = *(const bf8*)&zb[((size_t)(b * MM + sr * 16 + l16)) * CC + k0 + quad * 8];
#pragma unroll
        for (int sc = 0; sc < 2; sc++)
            bfr[sc] = *(const bf8*)&W[((size_t)(ct * 128 + w * 32 + sc * 16 + l16)) * CC + k0 + quad * 8];
#pragma unroll
        for (int sr = 0; sr < 4; sr++)
#pragma unroll
            for (int sc = 0; sc < 2; sc++)
                acc[sr][sc] = mfma16(afr[sr], bfr[sc], acc[sr][sc]);
    }
#pragma unroll
    for (int sr = 0; sr < 4; sr++)
#pragma unroll
        for (int sc = 0; sc < 2; sc++) {
            int col = ct * 128 + w * 32 + sc * 16 + l16;
            float bb = bias[col];
            int h = col >> 6, d = col & 63;
            if (which == 0) {
#pragma unroll
                for (int r = 0; r < 4; r++) {
                    int m = sr * 16 + quad * 4 + r;
                    kout[(((size_t)(b * HH + h)) * MM + m) * DD + d] = f2bf(acc[sr][sc][r] + bb);
                }
            } else {
                bf4 p;
#pragma unroll
                for (int r = 0; r < 4; r++) p[r] = f2bf(acc[sr][sc][r] + bb);
                *(bf4*)&vtout[(((size_t)(b * HH + h)) * DD + d) * MM + sr * 16 + quad * 4] = p;
            }
        }
}

// ======== shared staging macro for the two 128x128 GEMMs ========
// LDS per buffer: A tile 128x32 (4096 el) | B tile 128x32 (4096 el); double-buffered.
// dest is wave-uniform base + lane*16B (global_load_lds constraint) -> linear [row][32] layout.
#define STAGE_AB(Asrc, Bsrc, dstbase, kk)                                                             \
    do {                                                                                              \
        __bf16* _Ad = (dstbase);                                                                      \
        int _row = w * 16 + (l >> 2), _ch = l & 3;                                                    \
        gl2lds16(&(Asrc)[(arow0 + _row) * CC + (kk) + _ch * 8], &_Ad[w * 512]);                       \
        gl2lds16(&(Asrc)[(arow0 + 64 + _row) * CC + (kk) + _ch * 8], &_Ad[2048 + w * 512]);           \
        gl2lds16(&(Bsrc)[((size_t)(jt * 128) + _row) * CC + (kk) + _ch * 8], &_Ad[4096 + w * 512]);   \
        gl2lds16(&(Bsrc)[((size_t)(jt * 128) + 64 + _row) * CC + (kk) + _ch * 8], &_Ad[4096 + 2048 + w * 512]); \
    } while (0)

// ---------- K4: q = xb @ Wq^T + bq -> (b,n,c) bf16 ----------
// 2-phase double-buffered K-loop + XCD-chunked block swizzle + 2-wave-parallel epilogue.
__global__ __launch_bounds__(256, 4) void k_qproj(const __bf16* __restrict__ xb,
        const __bf16* __restrict__ Wq, const float* __restrict__ bq,
        __bf16* __restrict__ qb) {
    // XCD-chunked swizzle: 1536 blocks = 8 XCD x 192; the 6 jt-blocks sharing an
    // A row-stripe stay on one XCD's L2 (cuts A fetch ~6x -> ~1x).
    int orig = blockIdx.y * gridDim.x + blockIdx.x;
    int lid = (orig & 7) * 192 + (orig >> 3);
    int jt = lid % 6;
    size_t arow0 = (size_t)(lid / 6) * 128;

    __shared__ __align__(16) __bf16 smem[4 * 128 * 32];   // 32 KB: [buf][A|B][128][32]
    int t = threadIdx.x, w = t >> 6, l = t & 63, quad = l >> 4, l16 = l & 15;
    int wr = w & 1, wc = w >> 1;
    f4v acc[4][4];
#pragma unroll
    for (int i = 0; i < 4; i++) for (int j = 0; j < 4; j++) acc[i][j] = (f4v)0.0f;

    STAGE_AB(xb, Wq, smem, 0);
    asm volatile("s_waitcnt vmcnt(0)" ::: "memory");
    __builtin_amdgcn_s_barrier();

    for (int kt = 0; kt < 24; ++kt) {
        int cur = kt & 1;
        if (kt < 23) STAGE_AB(xb, Wq, smem + (cur ^ 1) * 8192, (kt + 1) * 32);
        const __bf16* As = smem + cur * 8192;
        const __bf16* Bs = As + 4096;
        bf8 afr[4], bfr[4];
#pragma unroll
        for (int sr = 0; sr < 4; sr++) afr[sr] = *(const bf8*)&As[(wr * 64 + sr * 16 + l16) * 32 + quad * 8];
#pragma unroll
        for (int sc = 0; sc < 4; sc++) bfr[sc] = *(const bf8*)&Bs[(wc * 64 + sc * 16 + l16) * 32 + quad * 8];
        __builtin_amdgcn_s_setprio(1);
#pragma unroll
        for (int sr = 0; sr < 4; sr++)
#pragma unroll
            for (int sc = 0; sc < 4; sc++)
                acc[sr][sc] = mfma16(afr[sr], bfr[sc], acc[sr][sc]);
        __builtin_amdgcn_s_setprio(0);
        if (kt < 23) asm volatile("s_waitcnt vmcnt(0)" ::: "memory");
        __builtin_amdgcn_s_barrier();
    }

    // epilogue: 2 phases, 2 waves write a 128x64 bf16 tile (pad 72 -> 16B-aligned rows), full-line stores
    __bf16* eb = smem;
    for (int p = 0; p < 2; ++p) {
        if (wc == p) {
#pragma unroll
            for (int sc = 0; sc < 4; sc++) {
                int col = jt * 128 + p * 64 + sc * 16 + l16;
                float bb = bq[col];
#pragma unroll
                for (int sr = 0; sr < 4; sr++)
#pragma unroll
                    for (int r = 0; r < 4; r++)
                        eb[(wr * 64 + sr * 16 + quad * 4 + r) * 72 + sc * 16 + l16] = f2bf(acc[sr][sc][r] + bb);
            }
        }
        __syncthreads();
#pragma unroll
        for (int i = 0; i < 4; i++) {
            int idx = t + 256 * i, row = idx >> 3, ch = idx & 7;
            *(bf8*)&qb[(arow0 + row) * CC + jt * 128 + p * 64 + ch * 8] = *(const bf8*)&eb[row * 72 + ch * 8];
        }
        __syncthreads();
    }
}

// ---------- K5: attention: s=q@k^T, softmax, o=p@v  (full-line o stores via ps) ----------
#define QS 72
__global__ __launch_bounds__(256) void k_attn(const __bf16* __restrict__ qb,
        const __bf16* __restrict__ kb, const __bf16* __restrict__ vt,
        __bf16* __restrict__ ob) {
    int n0 = blockIdx.x * 128, h = blockIdx.y, b = blockIdx.z;
    __shared__ __align__(16) __bf16 ps[128 * QS];
    int t = threadIdx.x, w = t >> 6, l = t & 63, quad = l >> 4, l16 = l & 15;
    size_t bh = (size_t)(b * HH + h);

    // phase 1: s = q @ k^T (K=64), operands direct-global
    f4v sacc[2][4];
#pragma unroll
    for (int i = 0; i < 2; i++) for (int j = 0; j < 4; j++) sacc[i][j] = (f4v)0.0f;
#pragma unroll
    for (int kc = 0; kc < 2; kc++) {
        bf8 afr[2], bfr[4];
#pragma unroll
        for (int sr = 0; sr < 2; sr++)
            afr[sr] = *(const bf8*)&qb[((size_t)(b * NN + n0 + w * 32 + sr * 16 + l16)) * CC + h * 64 + kc * 32 + quad * 8];
#pragma unroll
        for (int sc = 0; sc < 4; sc++)
            bfr[sc] = *(const bf8*)&kb[(bh * MM + sc * 16 + l16) * DD + kc * 32 + quad * 8];
#pragma unroll
        for (int sr = 0; sr < 2; sr++)
#pragma unroll
            for (int sc = 0; sc < 4; sc++)
                sacc[sr][sc] = mfma16(afr[sr], bfr[sc], sacc[sr][sc]);
    }
    // softmax over m (wave-private rows)
#pragma unroll
    for (int sr = 0; sr < 2; sr++) {
#pragma unroll
        for (int r = 0; r < 4; r++) {
            float mx = -1e30f;
#pragma unroll
            for (int sc = 0; sc < 4; sc++) mx = fmaxf(mx, sacc[sr][sc][r] * 0.125f);
#pragma unroll
            for (int off = 1; off < 16; off <<= 1) mx = fmaxf(mx, __shfl_xor(mx, off));
            float e[4]; float sum = 0.f;
#pragma unroll
            for (int sc = 0; sc < 4; sc++) { e[sc] = __expf(sacc[sr][sc][r] * 0.125f - mx); sum += e[sc]; }
#pragma unroll
            for (int off = 1; off < 16; off <<= 1) sum += __shfl_xor(sum, off);
            float inv = 1.0f / sum;
            int row = w * 32 + sr * 16 + quad * 4 + r;
#pragma unroll
            for (int sc = 0; sc < 4; sc++) ps[row * QS + sc * 16 + l16] = f2bf(e[sc] * inv);
        }
    }
    // phase 2: o = p @ v
    f4v oacc[2][4];
#pragma unroll
    for (int i = 0; i < 2; i++) for (int j = 0; j < 4; j++) oacc[i][j] = (f4v)0.0f;
#pragma unroll
    for (int kc = 0; kc < 2; kc++) {
        bf8 afr[2], bfr[4];
#pragma unroll
        for (int sr = 0; sr < 2; sr++)
            afr[sr] = *(const bf8*)&ps[(w * 32 + sr * 16 + l16) * QS + kc * 32 + quad * 8];
#pragma unroll
        for (int sc = 0; sc < 4; sc++)
            bfr[sc] = *(const bf8*)&vt[(bh * DD + sc * 16 + l16) * MM + kc * 32 + quad * 8];
#pragma unroll
        for (int sr = 0; sr < 2; sr++)
#pragma unroll
            for (int sc = 0; sc < 4; sc++)
                oacc[sr][sc] = mfma16(afr[sr], bfr[sc], oacc[sr][sc]);
    }
    // epilogue: o-tile (128x64) via ps -> full-line bf8 stores (wave-private rows, 1 barrier)
#pragma unroll
    for (int sr = 0; sr < 2; sr++)
#pragma unroll
        for (int sc = 0; sc < 4; sc++) {
            int row = w * 32 + sr * 16;
#pragma unroll
            for (int r = 0; r < 4; r++)
                ps[(row + quad * 4 + r) * QS + sc * 16 + l16] = f2bf(oacc[sr][sc][r]);
        }
    __syncthreads();
#pragma unroll
    for (int i = 0; i < 4; i++) {
        int idx = t + 256 * i, row = idx >> 3, ch = idx & 7;
        *(bf8*)&ob[((size_t)(b * NN + n0 + row)) * CC + h * 64 + ch * 8] = *(const bf8*)&ps[row * QS + ch * 8];
    }
}

// ---------- K6: out = o @ Wp^T + bp  (fp32 out) ----------
// same 2-phase double-buffer + XCD swizzle + 2-wave-parallel fp32 epilogue (pad 68 -> 16B-aligned rows)
__global__ __launch_bounds__(256, 4) void k_oproj(const __bf16* __restrict__ ob,
        const __bf16* __restrict__ Wp, const float* __restrict__ bp,
        float* __restrict__ out) {
    int orig = blockIdx.y * gridDim.x + blockIdx.x;
    int lid = (orig & 7) * 192 + (orig >> 3);
    int jt = lid % 6;
    size_t arow0 = (size_t)(lid / 6) * 128;

    __shared__ __align__(16) char smem_raw[128 * 68 * 4];  // 34 KB: max(staging 32K, fp32 epi 34K)
    __bf16* smem = (__bf16*)smem_raw;
    int t = threadIdx.x, w = t >> 6, l = t & 63, quad = l >> 4, l16 = l & 15;
    int wr = w & 1, wc = w >> 1;
    f4v acc[4][4];
#pragma unroll
    for (int i = 0; i < 4; i++) for (int j = 0; j < 4; j++) acc[i][j] = (f4v)0.0f;

    STAGE_AB(ob, Wp, smem, 0);
    asm volatile("s_waitcnt vmcnt(0)" ::: "memory");
    __builtin_amdgcn_s_barrier();

    for (int kt = 0; kt < 24; ++kt) {
        int cur = kt & 1;
        if (kt < 23) STAGE_AB(ob, Wp, smem + (cur ^ 1) * 8192, (kt + 1) * 32);
        const __bf16* As = smem + cur * 8192;
        const __bf16* Bs = As + 4096;
        bf8 afr[4], bfr[4];
#pragma unroll
        for (int sr = 0; sr < 4; sr++) afr[sr] = *(const bf8*)&As[(wr * 64 + sr * 16 + l16) * 32 + quad * 8];
#pragma unroll
        for (int sc = 0; sc < 4; sc++) bfr[sc] = *(const bf8*)&Bs[(wc * 64 + sc * 16 + l16) * 32 + quad * 8];
        __builtin_amdgcn_s_setprio(1);
#pragma unroll
        for (int sr = 0; sr < 4; sr++)
#pragma unroll
            for (int sc = 0; sc < 4; sc++)
                acc[sr][sc] = mfma16(afr[sr], bfr[sc], acc[sr][sc]);
        __builtin_amdgcn_s_setprio(0);
        if (kt < 23) asm volatile("s_waitcnt vmcnt(0)" ::: "memory");
        __builtin_amdgcn_s_barrier();
    }

    // epilogue: 2 phases, 2 waves write a 128x64 fp32 tile, full-line float4 stores
    float* eb = (float*)smem_raw;
    for (int p = 0; p < 2; ++p) {
        if (wc == p) {
#pragma unroll
            for (int sc = 0; sc < 4; sc++) {
                int col = jt * 128 + p * 64 + sc * 16 + l16;
                float bb = bp[col];
#pragma unroll
                for (int sr = 0; sr < 4; sr++)
#pragma unroll
                    for (int r = 0; r < 4; r++)
                        eb[(wr * 64 + sr * 16 + quad * 4 + r) * 68 + sc * 16 + l16] = acc[sr][sc][r] + bb;
            }
        }
        __syncthreads();
#pragma unroll
        for (int i = 0; i < 8; i++) {
            int idx = t + 256 * i, row = idx >> 4, c4 = idx & 15;
            *(float4*)&out[(arow0 + row) * CC + jt * 128 + p * 64 + c4 * 4] = *(const float4*)&eb[row * 68 + c4 * 4];
        }
        __syncthreads();
    }
}

extern "C" void kernel_launch(void* const* d_in, const int* in_sizes, int n_in,
                              void* d_out, int out_size, void* d_ws, size_t ws_size,
                              hipStream_t stream) {
    (void)in_sizes; (void)n_in; (void)out_size; (void)ws_size;
    const float* x  = (const float*)d_in[0];
    const float* Wc = (const float*)d_in[1];
    const float* bc = (const float*)d_in[2];
    const float* Wq = (const float*)d_in[3];
    const float* bq = (const float*)d_in[4];
    const float* Wk = (const float*)d_in[5];
    const float* bk = (const float*)d_in[6];
    const float* Wv = (const float*)d_in[7];
    const float* bv = (const float*)d_in[8];
    const float* Wp = (const float*)d_in[9];
    const float* bp = (const float*)d_in[10];
    float* out = (float*)d_out;

    char* ws = (char*)d_ws;
    size_t off = 0;
    auto alloc = [&](size_t bytes) { void* p = ws + off; off = (off + bytes + 255) & ~(size_t)255; return p; };
    __bf16* wc_b = (__bf16*)alloc((size_t)MM * CC * 2);
    __bf16* wq_b = (__bf16*)alloc((size_t)CC * CC * 2);
    __bf16* wk_b = (__bf16*)alloc((size_t)CC * CC * 2);
    __bf16* wv_b = (__bf16*)alloc((size_t)CC * CC * 2);
    __bf16* wp_b = (__bf16*)alloc((size_t)CC * CC * 2);
    __bf16* xb   = (__bf16*)alloc((size_t)BB * NN * CC * 2);
    __bf16* xt_o = (__bf16*)alloc((size_t)BB * NN * CC * 2);  // xt, reused as o
    __bf16* q_b  = (__bf16*)alloc((size_t)BB * NN * CC * 2);
    __bf16* c_bmn= (__bf16*)alloc((size_t)BB * MM * NN * 2);
    float*  z_f  = (float*) alloc((size_t)BB * MM * CC * 4);
    __bf16* z_b  = (__bf16*)alloc((size_t)BB * MM * CC * 2);
    __bf16* k_b  = (__bf16*)alloc((size_t)BB * HH * MM * DD * 2);
    __bf16* v_t  = (__bf16*)alloc((size_t)BB * HH * MM * DD * 2);

    k_cvtW<<<dim3((CC * CC / 4 + 255) / 256, 5), 256, 0, stream>>>(
        Wc, Wq, Wk, Wv, Wp, wc_b, wq_b, wk_b, wv_b, wp_b);

    k_cvtx<<<dim3(CC / 64, NN / 64, BB), 256, 0, stream>>>(x, xb, xt_o);
    k_cluster<<<dim3(NN / 128, BB), 256, 0, stream>>>(xb, wc_b, bc, c_bmn);
    k_z<<<dim3(CC / 64, BB), 256, 0, stream>>>(c_bmn, xt_o, z_f);
    k_znorm<<<(BB * MM) / 4, 256, 0, stream>>>(z_f, z_b);
    k_kv<<<dim3(CC / 128, BB, 2), 256, 0, stream>>>(z_b, wk_b, bk, wv_b, bv, k_b, v_t);
    k_qproj<<<dim3(CC / 128, (BB * NN) / 128), 256, 0, stream>>>(xb, wq_b, bq, q_b);
    k_attn<<<dim3(NN / 128, HH, BB), 256, 0, stream>>>(q_b, k_b, v_t, xt_o /* o reuses xt */);
    k_oproj<<<dim3(CC / 128, (BB * NN) / 128), 256, 0, stream>>>(xt_o, wp_b, bp, out);
}

// Round 2
// 271.390 us; speedup vs baseline: 1.1927x; 1.0359x over previous
//
#include <hip/hip_runtime.h>
#include <hip/hip_bf16.h>
#include <cstdint>

// ---- problem constants ----
#define BB 32
#define NN 1024
#define CC 768
#define MM 64
#define HH 12
#define DD 64

typedef float f4v __attribute__((ext_vector_type(4)));
typedef __bf16 bf8 __attribute__((ext_vector_type(8)));
typedef __bf16 bf4 __attribute__((ext_vector_type(4)));

__device__ __forceinline__ f4v mfma16(bf8 a, bf8 b, f4v c) {
    return __builtin_amdgcn_mfma_f32_16x16x32_bf16(a, b, c, 0, 0, 0);
}
__device__ __forceinline__ __bf16 f2bf(float f) { return (__bf16)f; }

__device__ __forceinline__ void gl2lds16(const void* g, void* lds) {
    __builtin_amdgcn_global_load_lds((const __attribute__((address_space(1))) void*)g,
                                     (__attribute__((address_space(3))) void*)lds, 16, 0, 0);
}

// ---------- all weight fp32 -> bf16 in ONE launch ----------
__global__ __launch_bounds__(256) void k_cvtW(
        const float* __restrict__ Wc, const float* __restrict__ Wq,
        const float* __restrict__ Wk, const float* __restrict__ Wv,
        const float* __restrict__ Wp,
        __bf16* __restrict__ wc, __bf16* __restrict__ wq,
        __bf16* __restrict__ wk, __bf16* __restrict__ wv,
        __bf16* __restrict__ wp) {
    const float* in; __bf16* out; int n4;
    switch (blockIdx.y) {
        case 0: in = Wc; out = wc; n4 = MM * CC / 4; break;
        case 1: in = Wq; out = wq; n4 = CC * CC / 4; break;
        case 2: in = Wk; out = wk; n4 = CC * CC / 4; break;
        case 3: in = Wv; out = wv; n4 = CC * CC / 4; break;
        default: in = Wp; out = wp; n4 = CC * CC / 4; break;
    }
    int i = blockIdx.x * 256 + threadIdx.x;
    if (i < n4) {
        float4 v = *(const float4*)&in[i * 4];
        bf4 o; o[0] = f2bf(v.x); o[1] = f2bf(v.y); o[2] = f2bf(v.z); o[3] = f2bf(v.w);
        *(bf4*)&out[i * 4] = o;
    }
}

// ---------- K0: x -> xb (b,n,c) bf16  AND  xt (b,c,n) bf16 (tiled transpose, full-line stores) ----------
#define TS 80
__global__ __launch_bounds__(256) void k_cvtx(const float* __restrict__ x,
        __bf16* __restrict__ xb, __bf16* __restrict__ xt) {
    int c0 = blockIdx.x * 64, n0 = blockIdx.y * 64, b = blockIdx.z;
    __shared__ __align__(16) __bf16 tile[64 * TS];
    int t = threadIdx.x;
#pragma unroll
    for (int i = 0; i < 4; i++) {
        int idx = t + 256 * i, r = idx >> 4, cq = idx & 15;
        float4 v = *(const float4*)&x[((size_t)(b * NN + n0 + r)) * CC + c0 + cq * 4];
        __bf16* d = &tile[r * TS + cq * 4];
        d[0] = f2bf(v.x); d[1] = f2bf(v.y); d[2] = f2bf(v.z); d[3] = f2bf(v.w);
    }
    __syncthreads();
#pragma unroll
    for (int i = 0; i < 2; i++) {
        int idx = t + 256 * i, r = idx >> 3, ch = idx & 7;
        *(bf8*)&xb[((size_t)(b * NN + n0 + r)) * CC + c0 + ch * 8] = *(const bf8*)&tile[r * TS + ch * 8];
    }
    // xt: one full 128B line (64 n) per c-row
#pragma unroll
    for (int i = 0; i < 2; i++) {
        int idx = t + 256 * i, c = idx >> 3, ch = idx & 7;
        bf8 v;
#pragma unroll
        for (int j = 0; j < 8; j++) v[j] = tile[(ch * 8 + j) * TS + c];
        *(bf8*)&xt[((size_t)(b * CC + c0 + c)) * NN + n0 + ch * 8] = v;
    }
}

// ---------- K1: c_bmn[b,m,n] = sigmoid(x@Wc^T + bc)/N   (LDS-free) ----------
__global__ __launch_bounds__(256) void k_cluster(const __bf16* __restrict__ xb,
        const __bf16* __restrict__ Wc, const float* __restrict__ bc,
        __bf16* __restrict__ cbmn) {
    int n0 = blockIdx.x * 128, b = blockIdx.y;
    int t = threadIdx.x, w = t >> 6, l = t & 63, quad = l >> 4, l16 = l & 15;
    f4v acc[2][4];
#pragma unroll
    for (int i = 0; i < 2; i++) for (int j = 0; j < 4; j++) acc[i][j] = (f4v)0.0f;
    for (int k0 = 0; k0 < CC; k0 += 32) {
        bf8 afr[2], bfr[4];
#pragma unroll
        for (int sr = 0; sr < 2; sr++)
            afr[sr] = *(const bf8*)&xb[((size_t)(b * NN + n0 + w * 32 + sr * 16 + l16)) * CC + k0 + quad * 8];
#pragma unroll
        for (int sc = 0; sc < 4; sc++)
            bfr[sc] = *(const bf8*)&Wc[(size_t)(sc * 16 + l16) * CC + k0 + quad * 8];
#pragma unroll
        for (int sr = 0; sr < 2; sr++)
#pragma unroll
            for (int sc = 0; sc < 4; sc++)
                acc[sr][sc] = mfma16(afr[sr], bfr[sc], acc[sr][sc]);
    }
#pragma unroll
    for (int sr = 0; sr < 2; sr++)
#pragma unroll
        for (int sc = 0; sc < 4; sc++) {
            int m = sc * 16 + l16;
            float bias = bc[m];
            bf4 p;
#pragma unroll
            for (int r = 0; r < 4; r++) {
                float val = acc[sr][sc][r] + bias;
                val = 1.0f / (1.0f + __expf(-val));
                p[r] = f2bf(val * (1.0f / 1024.0f));
            }
            *(bf4*)&cbmn[((size_t)(b * MM + m)) * NN + n0 + w * 32 + sr * 16 + quad * 4] = p;
        }
}

// ---------- K2: z[b,m,c] = sum_n c_bmn[b,m,n] * xt[b,c,n]   (LDS-free, fp32 out) ----------
__global__ __launch_bounds__(256) void k_z(const __bf16* __restrict__ cbmn,
        const __bf16* __restrict__ xt, float* __restrict__ z) {
    int c0 = blockIdx.x * 64, b = blockIdx.y;
    int t = threadIdx.x, w = t >> 6, l = t & 63, quad = l >> 4, l16 = l & 15;
    f4v acc[4];
#pragma unroll
    for (int j = 0; j < 4; j++) acc[j] = (f4v)0.0f;
    for (int n0 = 0; n0 < NN; n0 += 32) {
        bf8 afr = *(const bf8*)&cbmn[((size_t)(b * MM + w * 16 + l16)) * NN + n0 + quad * 8];
#pragma unroll
        for (int sc = 0; sc < 4; sc++) {
            bf8 bfr = *(const bf8*)&xt[((size_t)(b * CC + c0 + sc * 16 + l16)) * NN + n0 + quad * 8];
            acc[sc] = mfma16(afr, bfr, acc[sc]);
        }
    }
#pragma unroll
    for (int sc = 0; sc < 4; sc++) {
        int cc = c0 + sc * 16 + l16;
#pragma unroll
        for (int r = 0; r < 4; r++) {
            int m = w * 16 + quad * 4 + r;
            z[((size_t)(b * MM + m)) * CC + cc] = acc[sc][r];
        }
    }
}

// ---------- K2b: L2-normalize rows of z, write bf16 ----------
__global__ __launch_bounds__(256) void k_znorm(const float* __restrict__ z, __bf16* __restrict__ zb) {
    int w = threadIdx.x >> 6, l = threadIdx.x & 63;
    int row = blockIdx.x * 4 + w;
    const float* zr = &z[(size_t)row * CC];
    float v[12]; float ss = 0.f;
#pragma unroll
    for (int i = 0; i < 12; i++) { v[i] = zr[l + i * 64]; ss += v[i] * v[i]; }
#pragma unroll
    for (int off = 32; off; off >>= 1) ss += __shfl_xor(ss, off);
    float s = 1.0f / fmaxf(sqrtf(ss), 1e-12f);
    __bf16* zo = &zb[(size_t)row * CC];
#pragma unroll
    for (int i = 0; i < 12; i++) zo[l + i * 64] = f2bf(v[i] * s);
}

// ---------- K3: k = z@Wk^T+bk -> (b,h,m,d); v = z@Wv^T+bv -> TRANSPOSED (b,h,d,m) ----------
__global__ __launch_bounds__(256) void k_kv(const __bf16* __restrict__ zb,
        const __bf16* __restrict__ Wk, const float* __restrict__ bk,
        const __bf16* __restrict__ Wv, const float* __restrict__ bv,
        __bf16* __restrict__ kout, __bf16* __restrict__ vtout) {
    int ct = blockIdx.x, b = blockIdx.y, which = blockIdx.z;
    const __bf16* W = which ? Wv : Wk;
    const float* bias = which ? bv : bk;
    int t = threadIdx.x, w = t >> 6, l = t & 63, quad = l >> 4, l16 = l & 15;
    f4v acc[4][2];
#pragma unroll
    for (int i = 0; i < 4; i++) for (int j = 0; j < 2; j++) acc[i][j] = (f4v)0.0f;
    for (int k0 = 0; k0 < CC; k0 += 32) {
        bf8 afr[4], bfr[2];
#pragma unroll
        for (int sr = 0; sr < 4; sr++)
            afr[sr] = *(const bf8*)&zb[((size_t)(b * MM + sr * 16 + l16)) * CC + k0 + quad * 8];
#pragma unroll
        for (int sc = 0; sc < 2; sc++)
            bfr[sc] = *(const bf8*)&W[((size_t)(ct * 128 + w * 32 + sc * 16 + l16)) * CC + k0 + quad * 8];
#pragma unroll
        for (int sr = 0; sr < 4; sr++)
#pragma unroll
            for (int sc = 0; sc < 2; sc++)
                acc[sr][sc] = mfma16(afr[sr], bfr[sc], acc[sr][sc]);
    }
#pragma unroll
    for (int sr = 0; sr < 4; sr++)
#pragma unroll
        for (int sc = 0; sc < 2; sc++) {
            int col = ct * 128 + w * 32 + sc * 16 + l16;
            float bb = bias[col];
            int h = col >> 6, d = col & 63;
            if (which == 0) {
#pragma unroll
                for (int r = 0; r < 4; r++) {
                    int m = sr * 16 + quad * 4 + r;
                    kout[(((size_t)(b * HH + h)) * MM + m) * DD + d] = f2bf(acc[sr][sc][r] + bb);
                }
            } else {
                bf4 p;
#pragma unroll
                for (int r = 0; r < 4; r++) p[r] = f2bf(acc[sr][sc][r] + bb);
                *(bf4*)&vtout[(((size_t)(b * HH + h)) * DD + d) * MM + sr * 16 + quad * 4] = p;
            }
        }
}

// ======== shared staging macro for the two 128x128 GEMMs ========
// LDS per buffer: A tile 128x32 (4096 el) | B tile 128x32 (4096 el), 3 buffers (depth-3 pipeline).
// gl2lds dest is linear (wave base + lane*16B); bank-conflict fix is BOTH-sides:
// the per-lane GLOBAL chunk is pre-swizzled (ch = (l&3) ^ ((l>>3)&3)) and the ds_read
// applies the matching XOR (chunk ^ ((row>>1)&3)) -> 16-lane phase groups cover all 8
// 16B slot positions exactly twice -> conflict-free (2-way floor).
#define STAGE_AB(Asrc, Bsrc, dstbase, kk)                                                             \
    do {                                                                                              \
        __bf16* _Ad = (dstbase);                                                                      \
        int _row = w * 16 + (l >> 2), _ch = (l & 3) ^ ((l >> 3) & 3);                                 \
        gl2lds16(&(Asrc)[(arow0 + _row) * CC + (kk) + _ch * 8], &_Ad[w * 512]);                       \
        gl2lds16(&(Asrc)[(arow0 + 64 + _row) * CC + (kk) + _ch * 8], &_Ad[2048 + w * 512]);           \
        gl2lds16(&(Bsrc)[((size_t)(jt * 128) + _row) * CC + (kk) + _ch * 8], &_Ad[4096 + w * 512]);   \
        gl2lds16(&(Bsrc)[((size_t)(jt * 128) + 64 + _row) * CC + (kk) + _ch * 8], &_Ad[4096 + 2048 + w * 512]); \
    } while (0)

// depth-3 K-loop body: stage tile kt+2, wait for tile kt (counted vmcnt keeps
// kt+1/kt+2 loads in flight across the barrier), compute tile kt.
#define GEMM_KLOOP(Asrc, Bsrc)                                                                        \
    STAGE_AB(Asrc, Bsrc, smem, 0);                                                                    \
    STAGE_AB(Asrc, Bsrc, smem + 8192, 32);                                                            \
    _Pragma("unroll")                                                                                 \
    for (int kt = 0; kt < 24; ++kt) {                                                                 \
        if (kt < 22) STAGE_AB(Asrc, Bsrc, smem + ((kt + 2) % 3) * 8192, (kt + 2) * 32);               \
        if (kt < 22)      asm volatile("s_waitcnt vmcnt(8)" ::: "memory");                            \
        else if (kt == 22) asm volatile("s_waitcnt vmcnt(4)" ::: "memory");                           \
        else               asm volatile("s_waitcnt vmcnt(0)" ::: "memory");                           \
        __builtin_amdgcn_s_barrier();                                                                 \
        const __bf16* As = smem + (kt % 3) * 8192;                                                    \
        const __bf16* Bs = As + 4096;                                                                 \
        bf8 afr[4], bfr[4];                                                                           \
        _Pragma("unroll")                                                                             \
        for (int sr = 0; sr < 4; sr++)                                                                \
            afr[sr] = *(const bf8*)&As[(wr * 64 + sr * 16 + l16) * 32 + swz * 8];                     \
        _Pragma("unroll")                                                                             \
        for (int sc = 0; sc < 4; sc++)                                                                \
            bfr[sc] = *(const bf8*)&Bs[(wc * 64 + sc * 16 + l16) * 32 + swz * 8];                     \
        __builtin_amdgcn_s_setprio(1);                                                                \
        _Pragma("unroll")                                                                             \
        for (int sr = 0; sr < 4; sr++)                                                                \
            _Pragma("unroll")                                                                         \
            for (int sc = 0; sc < 4; sc++)                                                            \
                acc[sr][sc] = mfma16(afr[sr], bfr[sc], acc[sr][sc]);                                  \
        __builtin_amdgcn_s_setprio(0);                                                                \
        __builtin_amdgcn_s_barrier();                                                                 \
    }

// ---------- K4: q = xb @ Wq^T + bq -> (b,n,c) bf16 ----------
// depth-3 counted-vmcnt pipeline + conflict-free chunk swizzle + XCD-chunked block swizzle.
__global__ __launch_bounds__(256, 3) void k_qproj(const __bf16* __restrict__ xb,
        const __bf16* __restrict__ Wq, const float* __restrict__ bq,
        __bf16* __restrict__ qb) {
    // XCD-chunked swizzle: 1536 blocks = 8 XCD x 192; the 6 jt-blocks sharing an
    // A row-stripe stay on one XCD's L2.
    int orig = blockIdx.y * gridDim.x + blockIdx.x;
    int lid = (orig & 7) * 192 + (orig >> 3);
    int jt = lid % 6;
    size_t arow0 = (size_t)(lid / 6) * 128;

    __shared__ __align__(16) __bf16 smem[3 * 8192];   // 48 KB: 3 x [A|B][128][32]
    int t = threadIdx.x, w = t >> 6, l = t & 63, quad = l >> 4, l16 = l & 15;
    int wr = w & 1, wc = w >> 1;
    int swz = quad ^ ((l16 >> 1) & 3);   // read-side chunk swizzle (matches stage-side)
    f4v acc[4][4];
#pragma unroll
    for (int i = 0; i < 4; i++) for (int j = 0; j < 4; j++) acc[i][j] = (f4v)0.0f;

    GEMM_KLOOP(xb, Wq);

    // epilogue: 2 phases, 2 waves write a 128x64 bf16 tile (pad 72 -> 16B-aligned rows), full-line stores
    __bf16* eb = smem;
    for (int p = 0; p < 2; ++p) {
        if (wc == p) {
#pragma unroll
            for (int sc = 0; sc < 4; sc++) {
                int col = jt * 128 + p * 64 + sc * 16 + l16;
                float bb = bq[col];
#pragma unroll
                for (int sr = 0; sr < 4; sr++)
#pragma unroll
                    for (int r = 0; r < 4; r++)
                        eb[(wr * 64 + sr * 16 + quad * 4 + r) * 72 + sc * 16 + l16] = f2bf(acc[sr][sc][r] + bb);
            }
        }
        __syncthreads();
#pragma unroll
        for (int i = 0; i < 4; i++) {
            int idx = t + 256 * i, row = idx >> 3, ch = idx & 7;
            *(bf8*)&qb[(arow0 + row) * CC + jt * 128 + p * 64 + ch * 8] = *(const bf8*)&eb[row * 72 + ch * 8];
        }
        __syncthreads();
    }
}

// ---------- K5: attention: s=q@k^T, softmax, o=p@v  (full-line o stores via ps) ----------
#define QS 72
__global__ __launch_bounds__(256) void k_attn(const __bf16* __restrict__ qb,
        const __bf16* __restrict__ kb, const __bf16* __restrict__ vt,
        __bf16* __restrict__ ob) {
    int n0 = blockIdx.x * 128, h = blockIdx.y, b = blockIdx.z;
    __shared__ __align__(16) __bf16 ps[128 * QS];
    int t = threadIdx.x, w = t >> 6, l = t & 63, quad = l >> 4, l16 = l & 15;
    size_t bh = (size_t)(b * HH + h);

    // phase 1: s = q @ k^T (K=64), operands direct-global
    f4v sacc[2][4];
#pragma unroll
    for (int i = 0; i < 2; i++) for (int j = 0; j < 4; j++) sacc[i][j] = (f4v)0.0f;
#pragma unroll
    for (int kc = 0; kc < 2; kc++) {
        bf8 afr[2], bfr[4];
#pragma unroll
        for (int sr = 0; sr < 2; sr++)
            afr[sr] = *(const bf8*)&qb[((size_t)(b * NN + n0 + w * 32 + sr * 16 + l16)) * CC + h * 64 + kc * 32 + quad * 8];
#pragma unroll
        for (int sc = 0; sc < 4; sc++)
            bfr[sc] = *(const bf8*)&kb[(bh * MM + sc * 16 + l16) * DD + kc * 32 + quad * 8];
#pragma unroll
        for (int sr = 0; sr < 2; sr++)
#pragma unroll
            for (int sc = 0; sc < 4; sc++)
                sacc[sr][sc] = mfma16(afr[sr], bfr[sc], sacc[sr][sc]);
    }
    // softmax over m (wave-private rows)
#pragma unroll
    for (int sr = 0; sr < 2; sr++) {
#pragma unroll
        for (int r = 0; r < 4; r++) {
            float mx = -1e30f;
#pragma unroll
            for (int sc = 0; sc < 4; sc++) mx = fmaxf(mx, sacc[sr][sc][r] * 0.125f);
#pragma unroll
            for (int off = 1; off < 16; off <<= 1) mx = fmaxf(mx, __shfl_xor(mx, off));
            float e[4]; float sum = 0.f;
#pragma unroll
            for (int sc = 0; sc < 4; sc++) { e[sc] = __expf(sacc[sr][sc][r] * 0.125f - mx); sum += e[sc]; }
#pragma unroll
            for (int off = 1; off < 16; off <<= 1) sum += __shfl_xor(sum, off);
            float inv = 1.0f / sum;
            int row = w * 32 + sr * 16 + quad * 4 + r;
#pragma unroll
            for (int sc = 0; sc < 4; sc++) ps[row * QS + sc * 16 + l16] = f2bf(e[sc] * inv);
        }
    }
    // phase 2: o = p @ v
    f4v oacc[2][4];
#pragma unroll
    for (int i = 0; i < 2; i++) for (int j = 0; j < 4; j++) oacc[i][j] = (f4v)0.0f;
#pragma unroll
    for (int kc = 0; kc < 2; kc++) {
        bf8 afr[2], bfr[4];
#pragma unroll
        for (int sr = 0; sr < 2; sr++)
            afr[sr] = *(const bf8*)&ps[(w * 32 + sr * 16 + l16) * QS + kc * 32 + quad * 8];
#pragma unroll
        for (int sc = 0; sc < 4; sc++)
            bfr[sc] = *(const bf8*)&vt[(bh * DD + sc * 16 + l16) * MM + kc * 32 + quad * 8];
#pragma unroll
        for (int sr = 0; sr < 2; sr++)
#pragma unroll
            for (int sc = 0; sc < 4; sc++)
                oacc[sr][sc] = mfma16(afr[sr], bfr[sc], oacc[sr][sc]);
    }
    // epilogue: o-tile (128x64) via ps -> full-line bf8 stores (wave-private rows, 1 barrier)
#pragma unroll
    for (int sr = 0; sr < 2; sr++)
#pragma unroll
        for (int sc = 0; sc < 4; sc++) {
            int row = w * 32 + sr * 16;
#pragma unroll
            for (int r = 0; r < 4; r++)
                ps[(row + quad * 4 + r) * QS + sc * 16 + l16] = f2bf(oacc[sr][sc][r]);
        }
    __syncthreads();
#pragma unroll
    for (int i = 0; i < 4; i++) {
        int idx = t + 256 * i, row = idx >> 3, ch = idx & 7;
        *(bf8*)&ob[((size_t)(b * NN + n0 + row)) * CC + h * 64 + ch * 8] = *(const bf8*)&ps[row * QS + ch * 8];
    }
}

// ---------- K6: out = o @ Wp^T + bp  (fp32 out) ----------
// same depth-3 pipeline + swizzles + 2-wave-parallel fp32 epilogue (pad 68 -> 16B-aligned rows)
__global__ __launch_bounds__(256, 3) void k_oproj(const __bf16* __restrict__ ob,
        const __bf16* __restrict__ Wp, const float* __restrict__ bp,
        float* __restrict__ out) {
    int orig = blockIdx.y * gridDim.x + blockIdx.x;
    int lid = (orig & 7) * 192 + (orig >> 3);
    int jt = lid % 6;
    size_t arow0 = (size_t)(lid / 6) * 128;

    __shared__ __align__(16) __bf16 smem[3 * 8192];   // 48 KB: staging; epilogue fp32 (34 KB) fits
    int t = threadIdx.x, w = t >> 6, l = t & 63, quad = l >> 4, l16 = l & 15;
    int wr = w & 1, wc = w >> 1;
    int swz = quad ^ ((l16 >> 1) & 3);
    f4v acc[4][4];
#pragma unroll
    for (int i = 0; i < 4; i++) for (int j = 0; j < 4; j++) acc[i][j] = (f4v)0.0f;

    GEMM_KLOOP(ob, Wp);

    // epilogue: 2 phases, 2 waves write a 128x64 fp32 tile, full-line float4 stores
    float* eb = (float*)smem;
    for (int p = 0; p < 2; ++p) {
        if (wc == p) {
#pragma unroll
            for (int sc = 0; sc < 4; sc++) {
                int col = jt * 128 + p * 64 + sc * 16 + l16;
                float bb = bp[col];
#pragma unroll
                for (int sr = 0; sr < 4; sr++)
#pragma unroll
                    for (int r = 0; r < 4; r++)
                        eb[(wr * 64 + sr * 16 + quad * 4 + r) * 68 + sc * 16 + l16] = acc[sr][sc][r] + bb;
            }
        }
        __syncthreads();
#pragma unroll
        for (int i = 0; i < 8; i++) {
            int idx = t + 256 * i, row = idx >> 4, c4 = idx & 15;
            *(float4*)&out[(arow0 + row) * CC + jt * 128 + p * 64 + c4 * 4] = *(const float4*)&eb[row * 68 + c4 * 4];
        }
        __syncthreads();
    }
}

extern "C" void kernel_launch(void* const* d_in, const int* in_sizes, int n_in,
                              void* d_out, int out_size, void* d_ws, size_t ws_size,
                              hipStream_t stream) {
    (void)in_sizes; (void)n_in; (void)out_size; (void)ws_size;
    const float* x  = (const float*)d_in[0];
    const float* Wc = (const float*)d_in[1];
    const float* bc = (const float*)d_in[2];
    const float* Wq = (const float*)d_in[3];
    const float* bq = (const float*)d_in[4];
    const float* Wk = (const float*)d_in[5];
    const float* bk = (const float*)d_in[6];
    const float* Wv = (const float*)d_in[7];
    const float* bv = (const float*)d_in[8];
    const float* Wp = (const float*)d_in[9];
    const float* bp = (const float*)d_in[10];
    float* out = (float*)d_out;

    char* ws = (char*)d_ws;
    size_t off = 0;
    auto alloc = [&](size_t bytes) { void* p = ws + off; off = (off + bytes + 255) & ~(size_t)255; return p; };
    __bf16* wc_b = (__bf16*)alloc((size_t)MM * CC * 2);
    __bf16* wq_b = (__bf16*)alloc((size_t)CC * CC * 2);
    __bf16* wk_b = (__bf16*)alloc((size_t)CC * CC * 2);
    __bf16* wv_b = (__bf16*)alloc((size_t)CC * CC * 2);
    __bf16* wp_b = (__bf16*)alloc((size_t)CC * CC * 2);
    __bf16* xb   = (__bf16*)alloc((size_t)BB * NN * CC * 2);
    __bf16* xt_o = (__bf16*)alloc((size_t)BB * NN * CC * 2);  // xt, reused as o
    __bf16* q_b  = (__bf16*)alloc((size_t)BB * NN * CC * 2);
    __bf16* c_bmn= (__bf16*)alloc((size_t)BB * MM * NN * 2);
    float*  z_f  = (float*) alloc((size_t)BB * MM * CC * 4);
    __bf16* z_b  = (__bf16*)alloc((size_t)BB * MM * CC * 2);
    __bf16* k_b  = (__bf16*)alloc((size_t)BB * HH * MM * DD * 2);
    __bf16* v_t  = (__bf16*)alloc((size_t)BB * HH * MM * DD * 2);

    k_cvtW<<<dim3((CC * CC / 4 + 255) / 256, 5), 256, 0, stream>>>(
        Wc, Wq, Wk, Wv, Wp, wc_b, wq_b, wk_b, wv_b, wp_b);

    k_cvtx<<<dim3(CC / 64, NN / 64, BB), 256, 0, stream>>>(x, xb, xt_o);
    k_cluster<<<dim3(NN / 128, BB), 256, 0, stream>>>(xb, wc_b, bc, c_bmn);
    k_z<<<dim3(CC / 64, BB), 256, 0, stream>>>(c_bmn, xt_o, z_f);
    k_znorm<<<(BB * MM) / 4, 256, 0, stream>>>(z_f, z_b);
    k_kv<<<dim3(CC / 128, BB, 2), 256, 0, stream>>>(z_b, wk_b, bk, wv_b, bv, k_b, v_t);
    k_qproj<<<dim3(CC / 128, (BB * NN) / 128), 256, 0, stream>>>(xb, wq_b, bq, q_b);
    k_attn<<<dim3(NN / 128, HH, BB), 256, 0, stream>>>(q_b, k_b, v_t, xt_o /* o reuses xt */);
    k_oproj<<<dim3(CC / 128, (BB * NN) / 128), 256, 0, stream>>>(xt_o, wp_b, bp, out);
}